// Round 16
// baseline (2171.501 us; speedup 1.0000x reference)
//
#include <hip/hip_runtime.h>
#include <hip/hip_bf16.h>
#include <stdint.h>

#define VOCAB 32000
#define HIDDEN 512
#define TSEQ 1024
#define SENT 0x7F807F80u   // two +inf bf16 — unrepresentable in tanh/h0 data
#define NSCANBLK 32        // blocks 0..31: wave 0 scans 16 rows each
#define NBLK 256           // 1 block/CU, fully co-resident
#define NGEMMBLK (NBLK - NSCANBLK)
#define NTILE 2000         // 8 bm x 250 bn

typedef __attribute__((ext_vector_type(4))) float f32x4;
typedef __attribute__((ext_vector_type(8))) short short8;
typedef __attribute__((ext_vector_type(2))) unsigned uint2v;

union bfpack8 { short8 s; __hip_bfloat16 e[8]; };
union frag_u { short8 s; uint4 u; };

// ---------------- kernel: fill h rows 1..TSEQ with the sentinel ----------------
__global__ __launch_bounds__(256) void k_fill(uint4* __restrict__ p, int n4) {
  const int i = blockIdx.x * blockDim.x + threadIdx.x;
  if (i < n4) {
    uint4 v; v.x = SENT; v.y = SENT; v.z = SENT; v.w = SENT;
    p[i] = v;
  }
}

// ---- pre[t][j] = Wxh_w[j][idx[t]] + Wxh_b[j] + Whh_b[j];  h_bf[0] = bf16(h0) ----
__global__ __launch_bounds__(512) void k_pre(const int* __restrict__ idx,
                                             const float* __restrict__ h0,
                                             const float* __restrict__ Wxh_w,
                                             const float* __restrict__ Wxh_b,
                                             const float* __restrict__ Whh_b,
                                             float* __restrict__ pre,
                                             __hip_bfloat16* __restrict__ h_bf) {
  const int t = blockIdx.x;
  const int j = threadIdx.x;
  const int c = idx[t];
  pre[(size_t)t * HIDDEN + j] = Wxh_w[(size_t)j * VOCAB + c] + Wxh_b[j] + Whh_b[j];
  if (t == 0) h_bf[j] = __float2bfloat16(h0[j]);  // finite => never SENT
}

// device-coherent 16B load with intrinsic sentinel retry (single-asm-block).
__device__ __forceinline__ short8 poll16(const void* p) {
  short8 v;
  for (;;) {
    asm volatile("global_load_dwordx4 %0, %1, off sc0 sc1\n\ts_waitcnt vmcnt(0)"
                 : "=v"(v) : "v"(p));
    frag_u f; f.s = v;
    if ((f.u.x != SENT) & (f.u.y != SENT) & (f.u.z != SENT) & (f.u.w != SENT))
      return v;
  }
}

// ---------------- fused kernel: scan (blocks 0..31) + persistent GEMM ----------------
// Scan path: R15's proven protocol, with the poll upgraded to a 2-deep pipelined
//   sentinel poll implemented ENTIRELY inside one asm block (labels + scc
//   branches) — halves the poll period; accept exits WITHOUT draining the
//   partner quad (those regs stay live via "+v" ties into a deferred vmcnt(0)
//   after the MFMA phase, where the wait is free).
// GEMM path: unchanged from R15 (gated persistent tiles, poll16 backstop,
//   B f32->bf16 conversion folded into staging).
__global__ __launch_bounds__(256, 1) void k_fused(
    const float* __restrict__ pre, const float* __restrict__ Whh,
    __hip_bfloat16* __restrict__ h_bf, float* __restrict__ h_final,
    const float* __restrict__ Why_w, const float* __restrict__ Why_b,
    float* __restrict__ C) {
  __shared__ __align__(16) char sh[33792];  // union: scan 32KB+1KB | gemm 8KB+8KB

  const int blk = blockIdx.x;
  const int tid = threadIdx.x;

  if (blk < NSCANBLK) {
    // ===================== scan path (wave 0 only) =====================
    if (tid >= 64) return;
    short8 (*afrag)[64] = reinterpret_cast<short8 (*)[64]>(sh);          // 32 KB
    __hip_bfloat16* hstage = reinterpret_cast<__hip_bfloat16*>(sh + 32768);  // 1 KB

    const int wv = blk;
    const int l = tid;
    const int l15 = l & 15;
    const int l4 = l >> 4;
    const int base = wv * 16;

    // one-time: build A-fragments (W ~= hi(bf16) + lo(bf16)), stash in LDS
    {
      const float* wp = Whh + (size_t)(base + l15) * HIDDEN + l4 * 8;
#pragma unroll
      for (int kk = 0; kk < 16; ++kk) {
        const f32x4 a = *reinterpret_cast<const f32x4*>(wp + kk * 32);
        const f32x4 b = *reinterpret_cast<const f32x4*>(wp + kk * 32 + 4);
        bfpack8 hi, lo;
#pragma unroll
        for (int i = 0; i < 4; ++i) {
          hi.e[i] = __float2bfloat16(a[i]);
          lo.e[i] = __float2bfloat16(a[i] - __bfloat162float(hi.e[i]));
          hi.e[4 + i] = __float2bfloat16(b[i]);
          lo.e[4 + i] = __float2bfloat16(b[i] - __bfloat162float(hi.e[4 + i]));
        }
        afrag[2 * kk][l] = hi.s;
        afrag[2 * kk + 1][l] = lo.s;
      }
    }

    for (int t = 1; t <= TSEQ; ++t) {
      const float* pp = pre + (size_t)(t - 1) * HIDDEN + base + l4 * 4;
      const f32x4 pv = *reinterpret_cast<const f32x4*>(pp);

      // ---- 2-deep pipelined sentinel poll, whole loop in ONE asm block ----
      // lane l owns bytes [16l,16l+16) of row t-1; per-dword sentinel checks.
      // vmcnt(4) is FIFO-robust to older outstanding ops (they retire first).
      const __hip_bfloat16* hrow = h_bf + (size_t)(t - 1) * HIDDEN + l * 8;
      unsigned a0, a1, a2, a3, b0, b1, b2, b3, w;
      unsigned long long m0s, m1s;
      asm volatile(
          "global_load_dword %[a0], %[ad], off sc0 sc1\n\t"
          "global_load_dword %[a1], %[ad], off offset:4 sc0 sc1\n\t"
          "global_load_dword %[a2], %[ad], off offset:8 sc0 sc1\n\t"
          "global_load_dword %[a3], %[ad], off offset:12 sc0 sc1\n\t"
          "global_load_dword %[b0], %[ad], off sc0 sc1\n\t"
          "global_load_dword %[b1], %[ad], off offset:4 sc0 sc1\n\t"
          "global_load_dword %[b2], %[ad], off offset:8 sc0 sc1\n\t"
          "global_load_dword %[b3], %[ad], off offset:12 sc0 sc1\n\t"
          "LPOLL%=:\n\t"
          "s_waitcnt vmcnt(4)\n\t"                      // A quad complete
          "v_cmp_ne_u32 %[m0], %[sS], %[a0]\n\t"
          "v_cmp_ne_u32 %[m1], %[sS], %[a1]\n\t"
          "s_and_b64 %[m0], %[m0], %[m1]\n\t"
          "v_cmp_ne_u32 %[m1], %[sS], %[a2]\n\t"
          "s_and_b64 %[m0], %[m0], %[m1]\n\t"
          "v_cmp_ne_u32 %[m1], %[sS], %[a3]\n\t"
          "s_and_b64 %[m0], %[m0], %[m1]\n\t"
          "s_xor_b64 %[m0], %[m0], exec\n\t"            // SCC = (not all lanes ok)
          "s_cbranch_scc0 LACC_A%=\n\t"
          "global_load_dword %[a0], %[ad], off sc0 sc1\n\t"
          "global_load_dword %[a1], %[ad], off offset:4 sc0 sc1\n\t"
          "global_load_dword %[a2], %[ad], off offset:8 sc0 sc1\n\t"
          "global_load_dword %[a3], %[ad], off offset:12 sc0 sc1\n\t"
          "s_waitcnt vmcnt(4)\n\t"                      // B quad complete
          "v_cmp_ne_u32 %[m0], %[sS], %[b0]\n\t"
          "v_cmp_ne_u32 %[m1], %[sS], %[b1]\n\t"
          "s_and_b64 %[m0], %[m0], %[m1]\n\t"
          "v_cmp_ne_u32 %[m1], %[sS], %[b2]\n\t"
          "s_and_b64 %[m0], %[m0], %[m1]\n\t"
          "v_cmp_ne_u32 %[m1], %[sS], %[b3]\n\t"
          "s_and_b64 %[m0], %[m0], %[m1]\n\t"
          "s_xor_b64 %[m0], %[m0], exec\n\t"
          "s_cbranch_scc0 LACC_B%=\n\t"
          "global_load_dword %[b0], %[ad], off sc0 sc1\n\t"
          "global_load_dword %[b1], %[ad], off offset:4 sc0 sc1\n\t"
          "global_load_dword %[b2], %[ad], off offset:8 sc0 sc1\n\t"
          "global_load_dword %[b3], %[ad], off offset:12 sc0 sc1\n\t"
          "s_branch LPOLL%=\n\t"
          "LACC_B%=:\n\t"
          "s_mov_b32 %[w], 1\n\t"
          "s_branch LEND%=\n\t"
          "LACC_A%=:\n\t"
          "s_mov_b32 %[w], 0\n\t"
          "LEND%=:"
          : [a0] "=&v"(a0), [a1] "=&v"(a1), [a2] "=&v"(a2), [a3] "=&v"(a3),
            [b0] "=&v"(b0), [b1] "=&v"(b1), [b2] "=&v"(b2), [b3] "=&v"(b3),
            [w] "=&s"(w), [m0] "=&s"(m0s), [m1] "=&s"(m1s)
          : [ad] "v"(hrow), [sS] "s"(SENT)
          : "scc");
      // select the valid quad (the other quad may have loads still in flight;
      // its registers stay live until the deferred drain below)
      frag_u fsel;
      fsel.u.x = w ? b0 : a0;
      fsel.u.y = w ? b1 : a1;
      fsel.u.z = w ? b2 : a2;
      fsel.u.w = w ? b3 : a3;
      const short8 hv = fsel.s;

      // ---- LDS bounce: coalesced layout -> B-fragment layout ----
      *reinterpret_cast<short8*>(&hstage[l * 8]) = hv;  // ds_write_b128
      short8 bq[16];
#pragma unroll
      for (int kk = 0; kk < 16; ++kk)
        bq[kk] = *reinterpret_cast<const short8*>(&hstage[kk * 32 + l4 * 8]);

      f32x4 acc0 = {0.f, 0.f, 0.f, 0.f};
      f32x4 acc1 = {0.f, 0.f, 0.f, 0.f};
      f32x4 acc2 = {0.f, 0.f, 0.f, 0.f};
      f32x4 acc3 = {0.f, 0.f, 0.f, 0.f};
#pragma unroll
      for (int kk = 0; kk < 8; ++kk) {
        acc0 = __builtin_amdgcn_mfma_f32_16x16x32_bf16(afrag[2 * kk][l], bq[kk], acc0, 0, 0, 0);
        acc2 = __builtin_amdgcn_mfma_f32_16x16x32_bf16(afrag[2 * kk + 1][l], bq[kk], acc2, 0, 0, 0);
        acc1 = __builtin_amdgcn_mfma_f32_16x16x32_bf16(afrag[2 * (kk + 8)][l], bq[kk + 8], acc1, 0, 0, 0);
        acc3 = __builtin_amdgcn_mfma_f32_16x16x32_bf16(afrag[2 * (kk + 8) + 1][l], bq[kk + 8], acc3, 0, 0, 0);
      }
      const f32x4 acc = (acc0 + acc1) + (acc2 + acc3);

      // deferred drain: the partner quad's in-flight loads have landed by now;
      // ties keep a0..b3 registers reserved until here (no regalloc reuse).
      asm volatile("s_waitcnt vmcnt(0)"
                   : "+v"(a0), "+v"(a1), "+v"(a2), "+v"(a3),
                     "+v"(b0), "+v"(b1), "+v"(b2), "+v"(b3));

      float y[4];
#pragma unroll
      for (int q = 0; q < 4; ++q) {
        const float x = fminf(fmaxf(pv[q] + acc[q], -15.f), 15.f);
        const float e = __expf(2.f * x);
        y[q] = (e - 1.f) * __builtin_amdgcn_rcpf(e + 1.f);
      }

      if (l15 == 0) {  // lanes l4=0..3 publish rows base + l4*4 + q (8B each)
        union { uint2v u; __hip_bfloat16 e[4]; } pk;
#pragma unroll
        for (int q = 0; q < 4; ++q) pk.e[q] = __float2bfloat16(y[q]);
        __hip_bfloat16* ha = h_bf + (size_t)t * HIDDEN + base + l4 * 4;
        asm volatile("global_store_dwordx2 %0, %1, off sc0 sc1"
                     :: "v"(ha), "v"(pk.u) : "memory");  // fire and forget
        if (t == TSEQ) {
          const f32x4 fo = {y[0], y[1], y[2], y[3]};
          *reinterpret_cast<f32x4*>(h_final + base + l4 * 4) = fo;
        }
      }
    }
    return;
  }

  // ===================== persistent GEMM path (R15 verbatim) =====================
  __hip_bfloat16 (*As)[32] = reinterpret_cast<__hip_bfloat16 (*)[32]>(sh);         // 8 KB
  __hip_bfloat16 (*Bs)[32] = reinterpret_cast<__hip_bfloat16 (*)[32]>(sh + 8192);  // 8 KB

  const int lane = tid & 63;
  const int wid = tid >> 6;
  const int wr = (wid >> 1) * 64;
  const int wc = (wid & 1) * 64;
  const int l15g = lane & 15;
  const int kc = lane >> 4;
  const int sr = tid >> 1;
  const int sc = (tid & 1) * 16;
  const __hip_bfloat16* A = h_bf + HIDDEN;  // A row r = h after step r+1

  for (int tile = blk - NSCANBLK; tile < NTILE; tile += NGEMMBLK) {
    const int bm = tile / 250;
    const int bn = tile % 250;

    // gate: any dword of h_bf row min(bm*128+129, TSEQ) non-sentinel
    // => rows <= bm*128+128 fully visible (wave skew <= 1 step). bm=7 leans on
    // the poll16 staging backstop for the final rows.
    if (tid == 0) {
      const int sg = (bm * 128 + 129 < TSEQ) ? (bm * 128 + 129) : TSEQ;
      const unsigned* gp = reinterpret_cast<const unsigned*>(h_bf + (size_t)sg * HIDDEN);
      for (;;) {
        unsigned v;
        asm volatile("global_load_dword %0, %1, off sc0 sc1\n\ts_waitcnt vmcnt(0)"
                     : "=v"(v) : "v"(gp));
        if (v != SENT) break;
        asm volatile("s_sleep 16");
      }
    }
    __syncthreads();

    const __hip_bfloat16* Ag = A + (size_t)(bm * 128 + sr) * HIDDEN + sc;
    const float* BgF = Why_w + (size_t)(bn * 128 + sr) * HIDDEN + sc;

    f32x4 acc[4][4];
#pragma unroll
    for (int m = 0; m < 4; ++m)
#pragma unroll
      for (int n = 0; n < 4; ++n) {
        acc[m][n][0] = 0.f; acc[m][n][1] = 0.f; acc[m][n][2] = 0.f; acc[m][n][3] = 0.f;
      }

    for (int ks = 0; ks < HIDDEN; ks += 32) {
      __syncthreads();  // WAR on LDS
      // A staging: device-coherent sentinel-retry loads (backstop; rare post-gate)
      const short8 s0 = poll16(Ag + ks);
      const short8 s1 = poll16(Ag + ks + 8);
      *reinterpret_cast<short8*>(&As[sr][sc]) = s0;
      *reinterpret_cast<short8*>(&As[sr][sc + 8]) = s1;
      // B staging: f32 -> bf16 in-register conversion
      const float* bp = BgF + ks;
      const f32x4 x0 = *reinterpret_cast<const f32x4*>(bp);
      const f32x4 x1 = *reinterpret_cast<const f32x4*>(bp + 4);
      const f32x4 x2 = *reinterpret_cast<const f32x4*>(bp + 8);
      const f32x4 x3 = *reinterpret_cast<const f32x4*>(bp + 12);
      bfpack8 q0, q1;
#pragma unroll
      for (int i = 0; i < 4; ++i) {
        q0.e[i] = __float2bfloat16(x0[i]);
        q0.e[4 + i] = __float2bfloat16(x1[i]);
        q1.e[i] = __float2bfloat16(x2[i]);
        q1.e[4 + i] = __float2bfloat16(x3[i]);
      }
      *reinterpret_cast<short8*>(&Bs[sr][sc]) = q0.s;
      *reinterpret_cast<short8*>(&Bs[sr][sc + 8]) = q1.s;
      __syncthreads();

      short8 af[4], bfr[4];
#pragma unroll
      for (int m = 0; m < 4; ++m)
        af[m] = *reinterpret_cast<const short8*>(&As[wr + m * 16 + l15g][kc * 8]);
#pragma unroll
      for (int n = 0; n < 4; ++n)
        bfr[n] = *reinterpret_cast<const short8*>(&Bs[wc + n * 16 + l15g][kc * 8]);
#pragma unroll
      for (int m = 0; m < 4; ++m)
#pragma unroll
        for (int n = 0; n < 4; ++n)
          acc[m][n] = __builtin_amdgcn_mfma_f32_16x16x32_bf16(af[m], bfr[n], acc[m][n], 0, 0, 0);
    }

    // epilogue: C/D layout col = lane&15, row = (lane>>4)*4 + q
#pragma unroll
    for (int m = 0; m < 4; ++m) {
#pragma unroll
      for (int n = 0; n < 4; ++n) {
        const int vcol = bn * 128 + wc + n * 16 + l15g;
        const float bv = Why_b[vcol];
#pragma unroll
        for (int q = 0; q < 4; ++q) {
          const int trow = bm * 128 + wr + m * 16 + kc * 4 + q;
          C[(size_t)trow * VOCAB + vcol] = acc[m][n][q] + bv;
        }
      }
    }
    __syncthreads();  // all LDS reads done before next tile's staging
  }
}

extern "C" void kernel_launch(void* const* d_in, const int* in_sizes, int n_in,
                              void* d_out, int out_size, void* d_ws, size_t ws_size,
                              hipStream_t stream) {
  (void)in_sizes; (void)n_in; (void)out_size; (void)ws_size;

  const int*   idx   = (const int*)d_in[0];
  const float* h0    = (const float*)d_in[1];
  const float* Wxh_w = (const float*)d_in[2];
  const float* Wxh_b = (const float*)d_in[3];
  const float* Whh_w = (const float*)d_in[4];
  const float* Whh_b = (const float*)d_in[5];
  const float* Why_w = (const float*)d_in[6];
  const float* Why_b = (const float*)d_in[7];
  float* out = (float*)d_out;

  // workspace layout (bytes)
  char* ws = (char*)d_ws;
  float* pre = (float*)ws;                                   // 2,097,152
  __hip_bfloat16* h_bf = (__hip_bfloat16*)(ws + 2097152);    // (TSEQ+1)*512*2 = 1,049,600

  // sentinel-fill h rows 1..TSEQ (replay-safe: refilled every call)
  k_fill<<<(TSEQ * HIDDEN / 8 + 255) / 256, 256, 0, stream>>>(
      (uint4*)(h_bf + HIDDEN), TSEQ * HIDDEN / 8);
  k_pre<<<TSEQ, HIDDEN, 0, stream>>>(idx, h0, Wxh_w, Wxh_b, Whh_b, pre, h_bf);
  k_fused<<<NBLK, 256, 0, stream>>>(pre, Whh_w, h_bf, out + 32768000,
                                    Why_w, Why_b, out);
}

// Round 17
// 1467.814 us; speedup vs baseline: 1.4794x; 1.4794x over previous
//
#include <hip/hip_runtime.h>
#include <hip/hip_bf16.h>
#include <stdint.h>

#define VOCAB 32000
#define HIDDEN 512
#define TSEQ 1024
#define SENT 0x7F807F80u   // two +inf bf16 — unrepresentable in tanh/h0 data
#define NSCANBLK 32        // blocks 0..31: wave 0 scans 16 rows each
#define NBLK 256           // 1 block/CU, fully co-resident
#define NGEMMBLK (NBLK - NSCANBLK)
#define NTILE 2000         // 8 bm x 250 bn

typedef __attribute__((ext_vector_type(4))) float f32x4;
typedef __attribute__((ext_vector_type(8))) short short8;
typedef __attribute__((ext_vector_type(2))) unsigned uint2v;

union bfpack8 { short8 s; __hip_bfloat16 e[8]; };
union frag_u { short8 s; uint4 u; };

// ---------------- kernel: fill h rows 1..TSEQ with the sentinel ----------------
__global__ __launch_bounds__(256) void k_fill(uint4* __restrict__ p, int n4) {
  const int i = blockIdx.x * blockDim.x + threadIdx.x;
  if (i < n4) {
    uint4 v; v.x = SENT; v.y = SENT; v.z = SENT; v.w = SENT;
    p[i] = v;
  }
}

// ---- pre[t][j] = Wxh_w[j][idx[t]] + Wxh_b[j] + Whh_b[j];  h_bf[0] = bf16(h0) ----
__global__ __launch_bounds__(512) void k_pre(const int* __restrict__ idx,
                                             const float* __restrict__ h0,
                                             const float* __restrict__ Wxh_w,
                                             const float* __restrict__ Wxh_b,
                                             const float* __restrict__ Whh_b,
                                             float* __restrict__ pre,
                                             __hip_bfloat16* __restrict__ h_bf) {
  const int t = blockIdx.x;
  const int j = threadIdx.x;
  const int c = idx[t];
  pre[(size_t)t * HIDDEN + j] = Wxh_w[(size_t)j * VOCAB + c] + Wxh_b[j] + Whh_b[j];
  if (t == 0) h_bf[j] = __float2bfloat16(h0[j]);  // finite => never SENT
}

// device-coherent 16B load with intrinsic sentinel retry. Load + waitcnt live in
// ONE asm block — the ONLY proven-safe construct (R9/R13/R14: any detached
// in-flight load is corrupted by regalloc copy/spill placement; R16: wider
// poll pipelines lose to coherent-point contention).
__device__ __forceinline__ short8 poll16(const void* p) {
  short8 v;
  for (;;) {
    asm volatile("global_load_dwordx4 %0, %1, off sc0 sc1\n\ts_waitcnt vmcnt(0)"
                 : "=v"(v) : "v"(p));
    frag_u f; f.s = v;
    if ((f.u.x != SENT) & (f.u.y != SENT) & (f.u.z != SENT) & (f.u.w != SENT))
      return v;
  }
}

// ---------------- fused kernel: scan (blocks 0..31) + persistent GEMM ----------------
// Scan path: R8's proven protocol — single-wave participants, weights as hi+lo
//   bf16 fragments in a 32KB LDS carve, sentinel-in-data handoff through the
//   memory-side coherent point, single-asm-block dwordx4 polls (measured
//   optimum: deeper pipelining (R16) and backoff (R10) are both slower).
// GEMM path: persistent tiles gated on h-row availability (skew <= 1 step =>
//   any dword of row bm*128+129 non-sentinel implies rows <= bm*128+128 done);
//   poll16 A-staging is the correctness backstop; B converts f32->bf16 in
//   staging registers (k_convert deleted, its cost hidden under the scan).
__global__ __launch_bounds__(256, 1) void k_fused(
    const float* __restrict__ pre, const float* __restrict__ Whh,
    __hip_bfloat16* __restrict__ h_bf, float* __restrict__ h_final,
    const float* __restrict__ Why_w, const float* __restrict__ Why_b,
    float* __restrict__ C) {
  __shared__ __align__(16) char sh[33792];  // union: scan 32KB+1KB | gemm 8KB+8KB

  const int blk = blockIdx.x;
  const int tid = threadIdx.x;

  if (blk < NSCANBLK) {
    // ===================== scan path (wave 0 only) =====================
    if (tid >= 64) return;
    short8 (*afrag)[64] = reinterpret_cast<short8 (*)[64]>(sh);          // 32 KB
    __hip_bfloat16* hstage = reinterpret_cast<__hip_bfloat16*>(sh + 32768);  // 1 KB

    const int wv = blk;
    const int l = tid;
    const int l15 = l & 15;
    const int l4 = l >> 4;
    const int base = wv * 16;

    // one-time: build A-fragments (W ~= hi(bf16) + lo(bf16)), stash in LDS
    {
      const float* wp = Whh + (size_t)(base + l15) * HIDDEN + l4 * 8;
#pragma unroll
      for (int kk = 0; kk < 16; ++kk) {
        const f32x4 a = *reinterpret_cast<const f32x4*>(wp + kk * 32);
        const f32x4 b = *reinterpret_cast<const f32x4*>(wp + kk * 32 + 4);
        bfpack8 hi, lo;
#pragma unroll
        for (int i = 0; i < 4; ++i) {
          hi.e[i] = __float2bfloat16(a[i]);
          lo.e[i] = __float2bfloat16(a[i] - __bfloat162float(hi.e[i]));
          hi.e[4 + i] = __float2bfloat16(b[i]);
          lo.e[4 + i] = __float2bfloat16(b[i] - __bfloat162float(hi.e[4 + i]));
        }
        afrag[2 * kk][l] = hi.s;
        afrag[2 * kk + 1][l] = lo.s;
      }
    }
    // single wave: LDS producer==consumer; compiler orders via lgkmcnt

    for (int t = 1; t <= TSEQ; ++t) {
      const float* pp = pre + (size_t)(t - 1) * HIDDEN + base + l4 * 4;
      const f32x4 pv = *reinterpret_cast<const f32x4*>(pp);

      // coalesced sentinel poll: lane l owns bytes [16l,16l+16) of row t-1
      const __hip_bfloat16* hrow = h_bf + (size_t)(t - 1) * HIDDEN + l * 8;
      short8 hv;
      unsigned ok;
      do {
        asm volatile("global_load_dwordx4 %0, %1, off sc0 sc1\n\ts_waitcnt vmcnt(0)"
                     : "=&v"(hv) : "v"(hrow) : "memory");
        frag_u f; f.s = hv;
        ok = (unsigned)(f.u.x != SENT) & (unsigned)(f.u.y != SENT) &
             (unsigned)(f.u.z != SENT) & (unsigned)(f.u.w != SENT);
      } while (!__all(ok != 0u));

      // LDS bounce: coalesced layout -> B-fragment layout
      *reinterpret_cast<short8*>(&hstage[l * 8]) = hv;  // ds_write_b128
      short8 bq[16];
#pragma unroll
      for (int kk = 0; kk < 16; ++kk)
        bq[kk] = *reinterpret_cast<const short8*>(&hstage[kk * 32 + l4 * 8]);

      f32x4 acc0 = {0.f, 0.f, 0.f, 0.f};
      f32x4 acc1 = {0.f, 0.f, 0.f, 0.f};
      f32x4 acc2 = {0.f, 0.f, 0.f, 0.f};
      f32x4 acc3 = {0.f, 0.f, 0.f, 0.f};
#pragma unroll
      for (int kk = 0; kk < 8; ++kk) {
        acc0 = __builtin_amdgcn_mfma_f32_16x16x32_bf16(afrag[2 * kk][l], bq[kk], acc0, 0, 0, 0);
        acc2 = __builtin_amdgcn_mfma_f32_16x16x32_bf16(afrag[2 * kk + 1][l], bq[kk], acc2, 0, 0, 0);
        acc1 = __builtin_amdgcn_mfma_f32_16x16x32_bf16(afrag[2 * (kk + 8)][l], bq[kk + 8], acc1, 0, 0, 0);
        acc3 = __builtin_amdgcn_mfma_f32_16x16x32_bf16(afrag[2 * (kk + 8) + 1][l], bq[kk + 8], acc3, 0, 0, 0);
      }
      const f32x4 acc = (acc0 + acc1) + (acc2 + acc3);

      float y[4];
#pragma unroll
      for (int q = 0; q < 4; ++q) {
        const float x = fminf(fmaxf(pv[q] + acc[q], -15.f), 15.f);
        const float e = __expf(2.f * x);
        y[q] = (e - 1.f) * __builtin_amdgcn_rcpf(e + 1.f);
      }

      if (l15 == 0) {  // lanes l4=0..3 publish rows base + l4*4 + q (8B each)
        union { uint2v u; __hip_bfloat16 e[4]; } pk;
#pragma unroll
        for (int q = 0; q < 4; ++q) pk.e[q] = __float2bfloat16(y[q]);
        __hip_bfloat16* ha = h_bf + (size_t)t * HIDDEN + base + l4 * 4;
        asm volatile("global_store_dwordx2 %0, %1, off sc0 sc1"
                     :: "v"(ha), "v"(pk.u) : "memory");  // fire and forget
        if (t == TSEQ) {
          const f32x4 fo = {y[0], y[1], y[2], y[3]};
          *reinterpret_cast<f32x4*>(h_final + base + l4 * 4) = fo;
        }
      }
    }
    return;
  }

  // ===================== persistent GEMM path =====================
  __hip_bfloat16 (*As)[32] = reinterpret_cast<__hip_bfloat16 (*)[32]>(sh);         // 8 KB
  __hip_bfloat16 (*Bs)[32] = reinterpret_cast<__hip_bfloat16 (*)[32]>(sh + 8192);  // 8 KB

  const int lane = tid & 63;
  const int wid = tid >> 6;
  const int wr = (wid >> 1) * 64;
  const int wc = (wid & 1) * 64;
  const int l15g = lane & 15;
  const int kc = lane >> 4;
  const int sr = tid >> 1;
  const int sc = (tid & 1) * 16;
  const __hip_bfloat16* A = h_bf + HIDDEN;  // A row r = h after step r+1

  for (int tile = blk - NSCANBLK; tile < NTILE; tile += NGEMMBLK) {
    const int bm = tile / 250;
    const int bn = tile % 250;

    // gate: any dword of h_bf row min(bm*128+129, TSEQ) non-sentinel
    // => rows <= bm*128+128 fully visible (wave skew <= 1 step). bm=7 leans on
    // the poll16 staging backstop for the final rows.
    if (tid == 0) {
      const int sg = (bm * 128 + 129 < TSEQ) ? (bm * 128 + 129) : TSEQ;
      const unsigned* gp = reinterpret_cast<const unsigned*>(h_bf + (size_t)sg * HIDDEN);
      for (;;) {
        unsigned v;
        asm volatile("global_load_dword %0, %1, off sc0 sc1\n\ts_waitcnt vmcnt(0)"
                     : "=v"(v) : "v"(gp));
        if (v != SENT) break;
        asm volatile("s_sleep 16");
      }
    }
    __syncthreads();

    const __hip_bfloat16* Ag = A + (size_t)(bm * 128 + sr) * HIDDEN + sc;
    const float* BgF = Why_w + (size_t)(bn * 128 + sr) * HIDDEN + sc;

    f32x4 acc[4][4];
#pragma unroll
    for (int m = 0; m < 4; ++m)
#pragma unroll
      for (int n = 0; n < 4; ++n) {
        acc[m][n][0] = 0.f; acc[m][n][1] = 0.f; acc[m][n][2] = 0.f; acc[m][n][3] = 0.f;
      }

    for (int ks = 0; ks < HIDDEN; ks += 32) {
      __syncthreads();  // WAR on LDS
      // A staging: device-coherent sentinel-retry loads (backstop; rare post-gate)
      const short8 s0 = poll16(Ag + ks);
      const short8 s1 = poll16(Ag + ks + 8);
      *reinterpret_cast<short8*>(&As[sr][sc]) = s0;
      *reinterpret_cast<short8*>(&As[sr][sc + 8]) = s1;
      // B staging: f32 -> bf16 in-register conversion
      const float* bp = BgF + ks;
      const f32x4 x0 = *reinterpret_cast<const f32x4*>(bp);
      const f32x4 x1 = *reinterpret_cast<const f32x4*>(bp + 4);
      const f32x4 x2 = *reinterpret_cast<const f32x4*>(bp + 8);
      const f32x4 x3 = *reinterpret_cast<const f32x4*>(bp + 12);
      bfpack8 q0, q1;
#pragma unroll
      for (int i = 0; i < 4; ++i) {
        q0.e[i] = __float2bfloat16(x0[i]);
        q0.e[4 + i] = __float2bfloat16(x1[i]);
        q1.e[i] = __float2bfloat16(x2[i]);
        q1.e[4 + i] = __float2bfloat16(x3[i]);
      }
      *reinterpret_cast<short8*>(&Bs[sr][sc]) = q0.s;
      *reinterpret_cast<short8*>(&Bs[sr][sc + 8]) = q1.s;
      __syncthreads();

      short8 af[4], bfr[4];
#pragma unroll
      for (int m = 0; m < 4; ++m)
        af[m] = *reinterpret_cast<const short8*>(&As[wr + m * 16 + l15g][kc * 8]);
#pragma unroll
      for (int n = 0; n < 4; ++n)
        bfr[n] = *reinterpret_cast<const short8*>(&Bs[wc + n * 16 + l15g][kc * 8]);
#pragma unroll
      for (int m = 0; m < 4; ++m)
#pragma unroll
        for (int n = 0; n < 4; ++n)
          acc[m][n] = __builtin_amdgcn_mfma_f32_16x16x32_bf16(af[m], bfr[n], acc[m][n], 0, 0, 0);
    }

    // epilogue: C/D layout col = lane&15, row = (lane>>4)*4 + q
#pragma unroll
    for (int m = 0; m < 4; ++m) {
#pragma unroll
      for (int n = 0; n < 4; ++n) {
        const int vcol = bn * 128 + wc + n * 16 + l15g;
        const float bv = Why_b[vcol];
#pragma unroll
        for (int q = 0; q < 4; ++q) {
          const int trow = bm * 128 + wr + m * 16 + kc * 4 + q;
          C[(size_t)trow * VOCAB + vcol] = acc[m][n][q] + bv;
        }
      }
    }
    __syncthreads();  // all LDS reads done before next tile's staging
  }
}

extern "C" void kernel_launch(void* const* d_in, const int* in_sizes, int n_in,
                              void* d_out, int out_size, void* d_ws, size_t ws_size,
                              hipStream_t stream) {
  (void)in_sizes; (void)n_in; (void)out_size; (void)ws_size;

  const int*   idx   = (const int*)d_in[0];
  const float* h0    = (const float*)d_in[1];
  const float* Wxh_w = (const float*)d_in[2];
  const float* Wxh_b = (const float*)d_in[3];
  const float* Whh_w = (const float*)d_in[4];
  const float* Whh_b = (const float*)d_in[5];
  const float* Why_w = (const float*)d_in[6];
  const float* Why_b = (const float*)d_in[7];
  float* out = (float*)d_out;

  // workspace layout (bytes)
  char* ws = (char*)d_ws;
  float* pre = (float*)ws;                                   // 2,097,152
  __hip_bfloat16* h_bf = (__hip_bfloat16*)(ws + 2097152);    // (TSEQ+1)*512*2 = 1,049,600

  // sentinel-fill h rows 1..TSEQ (replay-safe: refilled every call)
  k_fill<<<(TSEQ * HIDDEN / 8 + 255) / 256, 256, 0, stream>>>(
      (uint4*)(h_bf + HIDDEN), TSEQ * HIDDEN / 8);
  k_pre<<<TSEQ, HIDDEN, 0, stream>>>(idx, h0, Wxh_w, Wxh_b, Whh_b, pre, h_bf);
  k_fused<<<NBLK, 256, 0, stream>>>(pre, Whh_w, h_bf, out + 32768000,
                                    Why_w, Why_b, out);
}